// Round 1
// baseline (890.897 us; speedup 1.0000x reference)
//
#include <hip/hip_runtime.h>
#include <hip/hip_bf16.h>

// Problem constants
constexpr int B_ = 512;
constexpr int T_ = 128;
constexpr int D_ = 768;
constexpr int CD_ = 192;
constexpr int SD_ = 128;
constexpr int P_ = 128;
constexpr int FEAT_ = 321;   // CD + SD + 1
constexpr float LN_EPS_ = 1e-5f;

// Workspace layout (in floats)
constexpr size_t REP_OFF  = 0;                       // rep: [B][2D]
constexpr size_t REP_SZ   = (size_t)B_ * 2 * D_;     // 786432
constexpr size_t DIRS_OFF = REP_OFF + REP_SZ;        // dirs_n: [P][D]
constexpr size_t DIRS_SZ  = (size_t)P_ * D_;         // 98304
constexpr size_t DOT_OFF  = DIRS_OFF + DIRS_SZ;      // d_ot: [B]
constexpr size_t PART_OFF = DOT_OFF + B_;            // ortho partials: [CD]

// ---------------------------------------------------------------------------
// Kernel 1: rep = [cls | mmean0 - mmean1]   (one block per batch)
// ---------------------------------------------------------------------------
__global__ __launch_bounds__(256) void k_rep(const float* __restrict__ H,
                                             const int* __restrict__ tt,
                                             const int* __restrict__ attn,
                                             float* __restrict__ rep) {
    int b = blockIdx.x;
    int tid = threadIdx.x;
    __shared__ float m0s[T_], m1s[T_];
    __shared__ int ncnt[2];
    if (tid < 2) ncnt[tid] = 0;
    __syncthreads();
    if (tid < T_) {
        int t = tt[b * T_ + tid];
        int a = attn[b * T_ + tid];
        float m0 = (t == 0 && a == 1) ? 1.f : 0.f;
        float m1 = (t == 1 && a == 1) ? 1.f : 0.f;
        m0s[tid] = m0;
        m1s[tid] = m1;
        if (m0 > 0.f) atomicAdd(&ncnt[0], 1);
        if (m1 > 0.f) atomicAdd(&ncnt[1], 1);
    }
    __syncthreads();
    float inv0 = 1.f / (float)max(ncnt[0], 1);
    float inv1 = 1.f / (float)max(ncnt[1], 1);
    const float* Hb = H + (size_t)b * T_ * D_;
    float* repb = rep + (size_t)b * 2 * D_;
    for (int d = tid; d < D_; d += 256) {
        float s0 = 0.f, s1 = 0.f;
        for (int t = 0; t < T_; ++t) {
            float h = Hb[(size_t)t * D_ + d];
            s0 = fmaf(h, m0s[t], s0);
            s1 = fmaf(h, m1s[t], s1);
        }
        repb[d] = Hb[d];                     // cls = H[b, 0, d]
        repb[D_ + d] = s0 * inv0 - s1 * inv1;
    }
}

// ---------------------------------------------------------------------------
// Kernel 2: dirs_n = dirs / ||dirs||  (one block per direction)
// ---------------------------------------------------------------------------
__global__ __launch_bounds__(256) void k_dirs(const float* __restrict__ dirs,
                                              float* __restrict__ dn) {
    int p = blockIdx.x;
    int tid = threadIdx.x;
    float s = 0.f;
    for (int d = tid; d < D_; d += 256) {
        float v = dirs[(size_t)p * D_ + d];
        s = fmaf(v, v, s);
    }
    __shared__ float red[256];
    red[tid] = s;
    __syncthreads();
    for (int off = 128; off > 0; off >>= 1) {
        if (tid < off) red[tid] += red[tid + off];
        __syncthreads();
    }
    float inv = 1.0f / sqrtf(red[0]);
    for (int d = tid; d < D_; d += 256) {
        dn[(size_t)p * D_ + d] = dirs[(size_t)p * D_ + d] * inv;
    }
}

// ---------------------------------------------------------------------------
// Kernel 3: fused proj GEMM (128x64 tile) + rank-sort + paired L1 diff + max
// grid = (B, 2): block handles batch b, columns [half*64, half*64+64)
// ---------------------------------------------------------------------------
constexpr int KB_ = 16;
constexpr int HSTR_ = KB_ + 4;   // 20 floats: breaks bank conflicts, keeps 16B align

__global__ __launch_bounds__(256) void k_projsort(const float* __restrict__ H,
                                                  const int* __restrict__ tt,
                                                  const int* __restrict__ attn,
                                                  const float* __restrict__ dn,
                                                  float* __restrict__ d_ot) {
    int b = blockIdx.x;
    int p0 = blockIdx.y * 64;
    int tid = threadIdx.x;

    __shared__ __align__(16) float proj[T_ * 64];                       // 32 KB
    __shared__ __align__(16) float stage[128 * HSTR_ + 64 * HSTR_];     // 15 KB (GEMM tiles)
    __shared__ float m0s[T_], m1s[T_];
    __shared__ int ncnt[2];
    __shared__ float dmax[64];

    float* Hs = stage;
    float* Ds = stage + 128 * HSTR_;
    // rank->t index tables overlay the (dead after GEMM) stage buffers
    unsigned char* xb = (unsigned char*)stage;           // [64][64]
    unsigned char* yb = xb + 64 * 64;                    // [64][64]

    // --- masks & counts ---
    if (tid < 2) ncnt[tid] = 0;
    __syncthreads();
    if (tid < T_) {
        int t = tt[b * T_ + tid];
        int a = attn[b * T_ + tid];
        float m0 = (t == 0 && a == 1) ? 1.f : 0.f;
        float m1 = (t == 1 && a == 1) ? 1.f : 0.f;
        m0s[tid] = m0;
        m1s[tid] = m1;
        if (m0 > 0.f) atomicAdd(&ncnt[0], 1);
        if (m1 > 0.f) atomicAdd(&ncnt[1], 1);
    }

    // --- GEMM: proj[t][p] = sum_k H[b,t,k] * dn[p0+p,k] ---
    int ty = tid >> 4, tx = tid & 15;
    float acc[8][4] = {};
    const float* Hb = H + (size_t)b * T_ * D_;
    int lrow = tid >> 2;            // 0..63
    int lk = (tid & 3) * 4;         // 0,4,8,12
    for (int k0 = 0; k0 < D_; k0 += KB_) {
        __syncthreads();            // protect prior-iter reads (and masks on iter 0)
        float4 h0 = *reinterpret_cast<const float4*>(Hb + (size_t)lrow * D_ + k0 + lk);
        float4 h1 = *reinterpret_cast<const float4*>(Hb + (size_t)(lrow + 64) * D_ + k0 + lk);
        float4 dd = *reinterpret_cast<const float4*>(dn + (size_t)(p0 + lrow) * D_ + k0 + lk);
        *reinterpret_cast<float4*>(Hs + lrow * HSTR_ + lk) = h0;
        *reinterpret_cast<float4*>(Hs + (lrow + 64) * HSTR_ + lk) = h1;
        *reinterpret_cast<float4*>(Ds + lrow * HSTR_ + lk) = dd;
        __syncthreads();
#pragma unroll
        for (int k = 0; k < KB_; ++k) {
            float a_[8], b_[4];
#pragma unroll
            for (int i = 0; i < 8; ++i) a_[i] = Hs[(ty + 16 * i) * HSTR_ + k];
#pragma unroll
            for (int j = 0; j < 4; ++j) b_[j] = Ds[(tx + 16 * j) * HSTR_ + k];
#pragma unroll
            for (int i = 0; i < 8; ++i)
#pragma unroll
                for (int j = 0; j < 4; ++j)
                    acc[i][j] = fmaf(a_[i], b_[j], acc[i][j]);
        }
    }
    __syncthreads();
#pragma unroll
    for (int i = 0; i < 8; ++i)
#pragma unroll
        for (int j = 0; j < 4; ++j)
            proj[(ty + 16 * i) * 64 + tx + 16 * j] = acc[i][j];
    __syncthreads();

    int n0 = ncnt[0], n1 = ncnt[1];
    int mm = min(n0, n1);            // attn==1 everywhere -> n0+n1=128 -> mm<=64
    int mmc = min(mm, 64);

    // --- rank phase: for each element, rank among same-mask elements in its column ---
    for (int g = tid; g < T_ * 16; g += 256) {   // 16 float4-groups of columns per row
        int t = g >> 4, p4 = g & 15;
        float me0 = m0s[t], me1 = m1s[t];
        if (me0 == 0.f && me1 == 0.f) continue;
        bool isX = (me0 > 0.f);
        const float* msame = isX ? m0s : m1s;
        float4 v = *reinterpret_cast<const float4*>(proj + t * 64 + p4 * 4);
        int c0 = 0, c1 = 0, c2 = 0, c3 = 0;
        for (int j = 0; j < T_; ++j) {
            float4 w = *reinterpret_cast<const float4*>(proj + j * 64 + p4 * 4);
            bool mk = msame[j] > 0.f;
            bool lt = j < t;
            c0 += (mk && (w.x < v.x || (w.x == v.x && lt)));
            c1 += (mk && (w.y < v.y || (w.y == v.y && lt)));
            c2 += (mk && (w.z < v.z || (w.z == v.z && lt)));
            c3 += (mk && (w.w < v.w || (w.w == v.w && lt)));
        }
        unsigned char* buf = isX ? xb : yb;
        int pb = p4 * 4;
        if (c0 < mmc) buf[c0 * 64 + pb + 0] = (unsigned char)t;
        if (c1 < mmc) buf[c1 * 64 + pb + 1] = (unsigned char)t;
        if (c2 < mmc) buf[c2 * 64 + pb + 2] = (unsigned char)t;
        if (c3 < mmc) buf[c3 * 64 + pb + 3] = (unsigned char)t;
    }
    __syncthreads();

    // --- paired diff per column, then max over columns ---
    if (tid < 64) {
        float s = 0.f;
        for (int r = 0; r < mmc; ++r) {
            float xv = proj[(int)xb[r * 64 + tid] * 64 + tid];
            float yv = proj[(int)yb[r * 64 + tid] * 64 + tid];
            s += fabsf(xv - yv);
        }
        dmax[tid] = s / (float)max(mm, 1);
    }
    __syncthreads();
    if (tid == 0) {
        float m = dmax[0];
        for (int i = 1; i < 64; ++i) m = fmaxf(m, dmax[i]);
        atomicMax((unsigned int*)&d_ot[b], __float_as_uint(m));  // m >= 0
    }
}

// ---------------------------------------------------------------------------
// Kernel 4: head — C/S GEMV, gate-fuse, LayerNorm, logits. 8 batches/block.
// ---------------------------------------------------------------------------
__global__ __launch_bounds__(256) void k_head(const float* __restrict__ rep,
                                              const float* __restrict__ Wc,
                                              const float* __restrict__ bc,
                                              const float* __restrict__ Ws,
                                              const float* __restrict__ bs,
                                              const float* __restrict__ gate,
                                              const float* __restrict__ lng,
                                              const float* __restrict__ lnb,
                                              const float* __restrict__ Wcls,
                                              const float* __restrict__ bcls,
                                              const float* __restrict__ d_ot,
                                              float* __restrict__ out) {
    int b0 = blockIdx.x * 8;
    int tid = threadIdx.x;
    __shared__ __align__(16) float repS[8 * 1536];   // 48 KB
    __shared__ float featS[8 * FEAT_];
    __shared__ float red[256];

    const float4* repg = reinterpret_cast<const float4*>(rep + (size_t)b0 * 1536);
    float4* repl = reinterpret_cast<float4*>(repS);
    for (int i = tid; i < 8 * 1536 / 4; i += 256) repl[i] = repg[i];
    __syncthreads();

    float g = 1.f / (1.f + expf(-gate[0]));

    for (int o = tid; o < CD_ + SD_; o += 256) {
        bool isC = o < CD_;
        const float* w = isC ? (Wc + (size_t)o * 1536) : (Ws + (size_t)(o - CD_) * 1536);
        float bias = isC ? bc[o] : bs[o - CD_];
        float scale = isC ? (1.f - g) : g;
        const float4* w4 = reinterpret_cast<const float4*>(w);
        float accv[8] = {};
        for (int k4 = 0; k4 < 384; ++k4) {
            float4 wv = w4[k4];
#pragma unroll
            for (int bi = 0; bi < 8; ++bi) {
                float4 rv = repl[bi * 384 + k4];
                float t = fmaf(wv.x, rv.x, fmaf(wv.y, rv.y, fmaf(wv.z, rv.z, wv.w * rv.w)));
                accv[bi] += t;
            }
        }
#pragma unroll
        for (int bi = 0; bi < 8; ++bi) featS[bi * FEAT_ + o] = (accv[bi] + bias) * scale;
    }
    if (tid < 8) featS[tid * FEAT_ + 320] = d_ot[b0 + tid];
    __syncthreads();

    for (int bi = 0; bi < 8; ++bi) {
        float s = 0.f, s2 = 0.f;
        for (int f = tid; f < FEAT_; f += 256) {
            float v = featS[bi * FEAT_ + f];
            s += v;
            s2 = fmaf(v, v, s2);
        }
        red[tid] = s;
        __syncthreads();
        for (int off = 128; off > 0; off >>= 1) {
            if (tid < off) red[tid] += red[tid + off];
            __syncthreads();
        }
        float mu = red[0] / (float)FEAT_;
        __syncthreads();
        red[tid] = s2;
        __syncthreads();
        for (int off = 128; off > 0; off >>= 1) {
            if (tid < off) red[tid] += red[tid + off];
            __syncthreads();
        }
        float var = fmaxf(red[0] / (float)FEAT_ - mu * mu, 0.f);
        float rstd = 1.0f / sqrtf(var + LN_EPS_);
        __syncthreads();

        float l0 = 0.f, l1 = 0.f;
        for (int f = tid; f < FEAT_; f += 256) {
            float nv = (featS[bi * FEAT_ + f] - mu) * rstd * lng[f] + lnb[f];
            l0 = fmaf(nv, Wcls[f], l0);
            l1 = fmaf(nv, Wcls[FEAT_ + f], l1);
        }
        red[tid] = l0;
        __syncthreads();
        for (int off = 128; off > 0; off >>= 1) {
            if (tid < off) red[tid] += red[tid + off];
            __syncthreads();
        }
        float L0 = red[0];
        __syncthreads();
        red[tid] = l1;
        __syncthreads();
        for (int off = 128; off > 0; off >>= 1) {
            if (tid < off) red[tid] += red[tid + off];
            __syncthreads();
        }
        if (tid == 0) {
            out[(size_t)(b0 + bi) * 2 + 0] = L0 + bcls[0];
            out[(size_t)(b0 + bi) * 2 + 1] = red[0] + bcls[1];
        }
        __syncthreads();
    }
}

// ---------------------------------------------------------------------------
// Kernel 5/6: ortho = mean((Wc @ Ws^T)^2), deterministic two-stage reduction
// ---------------------------------------------------------------------------
__global__ __launch_bounds__(256) void k_ortho(const float* __restrict__ Wc,
                                               const float* __restrict__ Ws,
                                               float* __restrict__ part) {
    int i = blockIdx.x;    // Wc row, 0..191
    int tid = threadIdx.x;
    __shared__ float wrow[1536];
    __shared__ float tmp[256];
    for (int k = tid; k < 1536; k += 256) wrow[k] = Wc[(size_t)i * 1536 + k];
    __syncthreads();
    int j = tid & 127, h = tid >> 7;    // split each dot across 2 threads
    const float* wsr = Ws + (size_t)j * 1536 + h * 768;
    const float* wr = wrow + h * 768;
    float s = 0.f;
    for (int k = 0; k < 768; ++k) s = fmaf(wr[k], wsr[k], s);
    tmp[tid] = s;
    __syncthreads();
    if (tid < 128) {
        float d = tmp[tid] + tmp[tid + 128];
        tmp[tid] = d * d;
    }
    __syncthreads();
    for (int off = 64; off > 0; off >>= 1) {
        if (tid < off) tmp[tid] += tmp[tid + off];
        __syncthreads();
    }
    if (tid == 0) part[i] = tmp[0];
}

__global__ __launch_bounds__(256) void k_ortho2(const float* __restrict__ part,
                                                float* __restrict__ out) {
    int tid = threadIdx.x;
    __shared__ float red[256];
    red[tid] = (tid < CD_) ? part[tid] : 0.f;
    __syncthreads();
    for (int off = 128; off > 0; off >>= 1) {
        if (tid < off) red[tid] += red[tid + off];
        __syncthreads();
    }
    if (tid == 0) out[(size_t)B_ * 2] = red[0] / (float)(CD_ * SD_);
}

// ---------------------------------------------------------------------------
extern "C" void kernel_launch(void* const* d_in, const int* in_sizes, int n_in,
                              void* d_out, int out_size, void* d_ws, size_t ws_size,
                              hipStream_t stream) {
    const float* H    = (const float*)d_in[0];
    const int*   tt   = (const int*)d_in[1];
    const int*   attn = (const int*)d_in[2];
    const float* Wc   = (const float*)d_in[3];
    const float* bc   = (const float*)d_in[4];
    const float* Ws   = (const float*)d_in[5];
    const float* bs   = (const float*)d_in[6];
    const float* gate = (const float*)d_in[7];
    const float* lng  = (const float*)d_in[8];
    const float* lnb  = (const float*)d_in[9];
    const float* Wcls = (const float*)d_in[10];
    const float* bcls = (const float*)d_in[11];
    const float* dirs = (const float*)d_in[12];

    float* ws   = (float*)d_ws;
    float* rep  = ws + REP_OFF;
    float* dn   = ws + DIRS_OFF;
    float* dot  = ws + DOT_OFF;
    float* part = ws + PART_OFF;
    float* out  = (float*)d_out;

    hipMemsetAsync(dot, 0, B_ * sizeof(float), stream);   // d_ot max-accumulator init (0.0f)

    k_rep<<<B_, 256, 0, stream>>>(H, tt, attn, rep);
    k_dirs<<<P_, 256, 0, stream>>>(dirs, dn);
    k_projsort<<<dim3(B_, 2), 256, 0, stream>>>(H, tt, attn, dn, dot);
    k_head<<<B_ / 8, 256, 0, stream>>>(rep, Wc, bc, Ws, bs, gate, lng, lnb, Wcls, bcls, dot, out);
    k_ortho<<<CD_, 256, 0, stream>>>(Wc, Ws, part);
    k_ortho2<<<1, 256, 0, stream>>>(part, out);
}

// Round 2
// 375.945 us; speedup vs baseline: 2.3698x; 2.3698x over previous
//
#include <hip/hip_runtime.h>
#include <hip/hip_bf16.h>

// Problem constants
constexpr int B_ = 512;
constexpr int T_ = 128;
constexpr int D_ = 768;
constexpr int CD_ = 192;
constexpr int SD_ = 128;
constexpr int P_ = 128;
constexpr int FEAT_ = 321;   // CD + SD + 1
constexpr float LN_EPS_ = 1e-5f;

// Workspace layout (in floats)
constexpr size_t REP_OFF  = 0;                       // rep: [B][2D]
constexpr size_t REP_SZ   = (size_t)B_ * 2 * D_;     // 786432
constexpr size_t DIRS_OFF = REP_OFF + REP_SZ;        // dirs_n: [P][D]
constexpr size_t DIRS_SZ  = (size_t)P_ * D_;         // 98304
constexpr size_t DOT_OFF  = DIRS_OFF + DIRS_SZ;      // d_ot: [B]
constexpr size_t PART_OFF = DOT_OFF + B_;            // ortho partials: [CD]

typedef __attribute__((ext_vector_type(8))) short short8;   // 8 bf16 (4 VGPRs)
typedef __attribute__((ext_vector_type(4))) float f32x4;

// float -> (bf16_hi, bf16_lo) RNE split: x ~= hi + lo, residual ~2^-16 |x|
__device__ inline void f2bf_split(float x, unsigned short& hi, unsigned short& lo) {
    unsigned u = __float_as_uint(x);
    unsigned short h = (unsigned short)((u + 0x7FFFu + ((u >> 16) & 1u)) >> 16);
    float hf = __uint_as_float((unsigned)h << 16);
    float l = x - hf;
    unsigned ul = __float_as_uint(l);
    lo = (unsigned short)((ul + 0x7FFFu + ((ul >> 16) & 1u)) >> 16);
    hi = h;
}

// ---------------------------------------------------------------------------
// Kernel 1: rep = [cls | mmean0 - mmean1]   (one block per batch)
// ---------------------------------------------------------------------------
__global__ __launch_bounds__(256) void k_rep(const float* __restrict__ H,
                                             const int* __restrict__ tt,
                                             const int* __restrict__ attn,
                                             float* __restrict__ rep) {
    int b = blockIdx.x;
    int tid = threadIdx.x;
    __shared__ float m0s[T_], m1s[T_];
    __shared__ int ncnt[2];
    if (tid < 2) ncnt[tid] = 0;
    __syncthreads();
    if (tid < T_) {
        int t = tt[b * T_ + tid];
        int a = attn[b * T_ + tid];
        float m0 = (t == 0 && a == 1) ? 1.f : 0.f;
        float m1 = (t == 1 && a == 1) ? 1.f : 0.f;
        m0s[tid] = m0;
        m1s[tid] = m1;
        if (m0 > 0.f) atomicAdd(&ncnt[0], 1);
        if (m1 > 0.f) atomicAdd(&ncnt[1], 1);
    }
    __syncthreads();
    float inv0 = 1.f / (float)max(ncnt[0], 1);
    float inv1 = 1.f / (float)max(ncnt[1], 1);
    const float* Hb = H + (size_t)b * T_ * D_;
    float* repb = rep + (size_t)b * 2 * D_;
    for (int d = tid; d < D_; d += 256) {
        float s0 = 0.f, s1 = 0.f;
        for (int t = 0; t < T_; ++t) {
            float h = Hb[(size_t)t * D_ + d];
            s0 = fmaf(h, m0s[t], s0);
            s1 = fmaf(h, m1s[t], s1);
        }
        repb[d] = Hb[d];                     // cls = H[b, 0, d]
        repb[D_ + d] = s0 * inv0 - s1 * inv1;
    }
}

// ---------------------------------------------------------------------------
// Kernel 2: dirs_n = dirs / ||dirs||  (one block per direction)
// ---------------------------------------------------------------------------
__global__ __launch_bounds__(256) void k_dirs(const float* __restrict__ dirs,
                                              float* __restrict__ dn) {
    int p = blockIdx.x;
    int tid = threadIdx.x;
    float s = 0.f;
    for (int d = tid; d < D_; d += 256) {
        float v = dirs[(size_t)p * D_ + d];
        s = fmaf(v, v, s);
    }
    __shared__ float red[256];
    red[tid] = s;
    __syncthreads();
    for (int off = 128; off > 0; off >>= 1) {
        if (tid < off) red[tid] += red[tid + off];
        __syncthreads();
    }
    float inv = 1.0f / sqrtf(red[0]);
    for (int d = tid; d < D_; d += 256) {
        dn[(size_t)p * D_ + d] = dirs[(size_t)p * D_ + d] * inv;
    }
}

// ---------------------------------------------------------------------------
// Kernel 3: MFMA proj GEMM (128x64 tile, bf16 hi/lo 3-pass) + key-rank + diff
// grid = (B, 2): block handles batch b, dir columns [half*64, half*64+64)
// ---------------------------------------------------------------------------
constexpr int KB_ = 32;          // K-step
constexpr int SA_ = 40;          // LDS stride (bf16 elems): 80 B, 16B-aligned, conflict-benign
// stage offsets in ushorts
constexpr int AHI_ = 0;                  // [128][40]
constexpr int ALO_ = 128 * SA_;          // 5120
constexpr int BHI_ = 2 * 128 * SA_;      // 10240, [64][40]
constexpr int BLO_ = BHI_ + 64 * SA_;    // 12800
constexpr int STAGE_U16_ = BLO_ + 64 * SA_;  // 15360 ushorts = 30720 B

__global__ __launch_bounds__(256) void k_projsort(const float* __restrict__ H,
                                                  const int* __restrict__ tt,
                                                  const int* __restrict__ attn,
                                                  const float* __restrict__ dn,
                                                  float* __restrict__ d_ot) {
    const int b = blockIdx.x;
    const int p0 = blockIdx.y * 64;
    const int tid = threadIdx.x;

    __shared__ float proj[T_ * 64];                              // 32 KB
    __shared__ __align__(16) unsigned short stage[STAGE_U16_];   // 30 KB (GEMM tiles)
    __shared__ float m0s[T_], m1s[T_];
    __shared__ unsigned char rlist[T_];
    __shared__ int ncnt[2];
    __shared__ float dred[256];

    // rank->t index tables overlay the (dead after GEMM) stage buffer
    unsigned char* xb = (unsigned char*)stage;           // [64][64]
    unsigned char* yb = xb + 64 * 64;                    // [64][64]

    // --- phase 0: masks, counts, group-compacted row list ---
    if (tid < 2) ncnt[tid] = 0;
    __syncthreads();
    if (tid < T_) {
        int t = tt[b * T_ + tid];
        int a = attn[b * T_ + tid];
        float m0 = (t == 0 && a == 1) ? 1.f : 0.f;
        float m1 = (t == 1 && a == 1) ? 1.f : 0.f;
        m0s[tid] = m0;
        m1s[tid] = m1;
        if (m0 > 0.f) atomicAdd(&ncnt[0], 1);
        if (m1 > 0.f) atomicAdd(&ncnt[1], 1);
    }
    __syncthreads();
    const int n0 = ncnt[0], n1 = ncnt[1];
    const int ntot = n0 + n1;
    if (tid < T_) {
        float me0 = m0s[tid], me1 = m1s[tid];
        if (me0 > 0.f || me1 > 0.f) {
            bool g1 = (me1 > 0.f);
            const float* ms = g1 ? m1s : m0s;
            int pos = g1 ? n0 : 0;
            for (int j = 0; j < tid; ++j) pos += (ms[j] > 0.f) ? 1 : 0;
            rlist[pos] = (unsigned char)tid;
        }
    }
    // (ordered before stage use by the first __syncthreads in the K-loop)

    // --- phase 1: GEMM proj[t][p] = sum_k H[b,t,k] * dn[p0+p,k] via MFMA ---
    const int wv = tid >> 6;          // wave 0..3
    const int wr = wv >> 1;           // row half
    const int wc = wv & 1;            // col half
    const int lane = tid & 63;
    const int fr = lane & 15;         // fragment row/col
    const int fk = (lane >> 4) * 8;   // fragment k offset
    const float* Hb = H + (size_t)b * T_ * D_;

    f32x4 acc[4][2];
#pragma unroll
    for (int m = 0; m < 4; ++m)
#pragma unroll
        for (int n = 0; n < 2; ++n) acc[m][n] = (f32x4){0.f, 0.f, 0.f, 0.f};

    for (int k0 = 0; k0 < D_; k0 += KB_) {
        __syncthreads();   // previous-iter frag reads done (also orders phase 0 on iter 0)
        // stage A: 128 rows x 32 k  (4 float4 chunks / thread)
#pragma unroll
        for (int j = 0; j < 4; ++j) {
            int c = tid + 256 * j;
            int row = c >> 3;
            int kq = (c & 7) * 4;
            float4 h = *reinterpret_cast<const float4*>(Hb + (size_t)row * D_ + k0 + kq);
            ushort4 vh, vl;
            f2bf_split(h.x, vh.x, vl.x);
            f2bf_split(h.y, vh.y, vl.y);
            f2bf_split(h.z, vh.z, vl.z);
            f2bf_split(h.w, vh.w, vl.w);
            *reinterpret_cast<ushort4*>(&stage[AHI_ + row * SA_ + kq]) = vh;
            *reinterpret_cast<ushort4*>(&stage[ALO_ + row * SA_ + kq]) = vl;
        }
        // stage B: 64 rows x 32 k (2 chunks / thread)
#pragma unroll
        for (int j = 0; j < 2; ++j) {
            int c = tid + 256 * j;
            int row = c >> 3;
            int kq = (c & 7) * 4;
            float4 h = *reinterpret_cast<const float4*>(dn + (size_t)(p0 + row) * D_ + k0 + kq);
            ushort4 vh, vl;
            f2bf_split(h.x, vh.x, vl.x);
            f2bf_split(h.y, vh.y, vl.y);
            f2bf_split(h.z, vh.z, vl.z);
            f2bf_split(h.w, vh.w, vl.w);
            *reinterpret_cast<ushort4*>(&stage[BHI_ + row * SA_ + kq]) = vh;
            *reinterpret_cast<ushort4*>(&stage[BLO_ + row * SA_ + kq]) = vl;
        }
        __syncthreads();
        short8 a_hi[4], a_lo[4], b_hi[2], b_lo[2];
#pragma unroll
        for (int m = 0; m < 4; ++m) {
            int r = 64 * wr + 16 * m + fr;
            a_hi[m] = *reinterpret_cast<const short8*>(&stage[AHI_ + r * SA_ + fk]);
            a_lo[m] = *reinterpret_cast<const short8*>(&stage[ALO_ + r * SA_ + fk]);
        }
#pragma unroll
        for (int n = 0; n < 2; ++n) {
            int r = 32 * wc + 16 * n + fr;
            b_hi[n] = *reinterpret_cast<const short8*>(&stage[BHI_ + r * SA_ + fk]);
            b_lo[n] = *reinterpret_cast<const short8*>(&stage[BLO_ + r * SA_ + fk]);
        }
#pragma unroll
        for (int m = 0; m < 4; ++m)
#pragma unroll
            for (int n = 0; n < 2; ++n) {
                acc[m][n] = __builtin_amdgcn_mfma_f32_16x16x32_bf16(a_hi[m], b_hi[n], acc[m][n], 0, 0, 0);
                acc[m][n] = __builtin_amdgcn_mfma_f32_16x16x32_bf16(a_hi[m], b_lo[n], acc[m][n], 0, 0, 0);
                acc[m][n] = __builtin_amdgcn_mfma_f32_16x16x32_bf16(a_lo[m], b_hi[n], acc[m][n], 0, 0, 0);
            }
    }
    __syncthreads();
    // write proj: C/D layout col=lane&15, row=(lane>>4)*4+reg
#pragma unroll
    for (int m = 0; m < 4; ++m)
#pragma unroll
        for (int n = 0; n < 2; ++n) {
            int row0 = 64 * wr + 16 * m + (lane >> 4) * 4;
            int col = 32 * wc + 16 * n + fr;
#pragma unroll
            for (int r = 0; r < 4; ++r) proj[(row0 + r) * 64 + col] = acc[m][n][r];
        }
    __syncthreads();

    // --- phase 2: ranking via sortable-u32 keys ---
    // key = (group<<31) | (su>>8<<7) | pos : group bit makes cross-group compares
    // self-cancelling; pos (list position, t-ordered within group) breaks ties.
    const int mmv = min(n0, n1);      // <= 64 since n0+n1 <= 128
    const int c = tid & 63;
    const int q = tid >> 6;           // wave-uniform
    unsigned kv[32];
    int cnt[32];
#pragma unroll
    for (int ii = 0; ii < 32; ++ii) {
        int p = q * 32 + ii;
        unsigned key = 0xFFFFFFFFu;
        if (p < ntot) {
            int t = rlist[p];
            unsigned u = __float_as_uint(proj[t * 64 + c]);
            unsigned su = u ^ (unsigned)(((int)u >> 31) | 0x80000000);
            key = ((unsigned)(p >= n0) << 31) | ((su >> 8) << 7) | (unsigned)p;
        }
        kv[ii] = key;
        cnt[ii] = 0;
    }
    int lo, hi;
    {
        int plo = q * 32, phi = q * 32 + 32;
        if (phi <= n0)      { lo = 0;  hi = n0;   }   // pure group-0 chunk
        else if (plo >= n0) { lo = n0; hi = ntot; }   // pure group-1 chunk
        else                { lo = 0;  hi = ntot; }   // straddler
    }
    for (int j = lo; j < hi; ++j) {
        int tj = rlist[j];
        unsigned u = __float_as_uint(proj[tj * 64 + c]);
        unsigned su = u ^ (unsigned)(((int)u >> 31) | 0x80000000);
        unsigned kw = ((unsigned)(j >= n0) << 31) | ((su >> 8) << 7) | (unsigned)j;
#pragma unroll
        for (int ii = 0; ii < 32; ++ii) cnt[ii] += (kw < kv[ii]) ? 1 : 0;
    }
#pragma unroll
    for (int ii = 0; ii < 32; ++ii) {
        int p = q * 32 + ii;
        if (p < ntot) {
            int rank = cnt[ii] - ((p >= n0 && lo == 0) ? n0 : 0);
            if (rank < mmv) {
                unsigned char* buf = (p >= n0) ? yb : xb;
                buf[rank * 64 + c] = rlist[p];
            }
        }
    }
    __syncthreads();

    // --- phase 3: paired diff per column, max over columns ---
    float part = 0.f;
    for (int r = q; r < mmv; r += 4) {
        int xt = xb[r * 64 + c], yt = yb[r * 64 + c];
        part += fabsf(proj[xt * 64 + c] - proj[yt * 64 + c]);
    }
    dred[tid] = part;
    __syncthreads();
    if (tid < 64) {
        float s = dred[tid] + dred[tid + 64] + dred[tid + 128] + dred[tid + 192];
        dred[tid] = s / (float)max(mmv, 1);
    }
    __syncthreads();
    if (tid == 0) {
        float m = dred[0];
        for (int i = 1; i < 64; ++i) m = fmaxf(m, dred[i]);
        atomicMax((unsigned int*)&d_ot[b], __float_as_uint(m));  // m >= 0
    }
}

// ---------------------------------------------------------------------------
// Kernel 4: head — C/S GEMV, gate-fuse, LayerNorm, logits. 8 batches/block.
// ---------------------------------------------------------------------------
__global__ __launch_bounds__(256) void k_head(const float* __restrict__ rep,
                                              const float* __restrict__ Wc,
                                              const float* __restrict__ bc,
                                              const float* __restrict__ Ws,
                                              const float* __restrict__ bs,
                                              const float* __restrict__ gate,
                                              const float* __restrict__ lng,
                                              const float* __restrict__ lnb,
                                              const float* __restrict__ Wcls,
                                              const float* __restrict__ bcls,
                                              const float* __restrict__ d_ot,
                                              float* __restrict__ out) {
    int b0 = blockIdx.x * 8;
    int tid = threadIdx.x;
    __shared__ __align__(16) float repS[8 * 1536];   // 48 KB
    __shared__ float featS[8 * FEAT_];
    __shared__ float red[256];

    const float4* repg = reinterpret_cast<const float4*>(rep + (size_t)b0 * 1536);
    float4* repl = reinterpret_cast<float4*>(repS);
    for (int i = tid; i < 8 * 1536 / 4; i += 256) repl[i] = repg[i];
    __syncthreads();

    float g = 1.f / (1.f + expf(-gate[0]));

    for (int o = tid; o < CD_ + SD_; o += 256) {
        bool isC = o < CD_;
        const float* w = isC ? (Wc + (size_t)o * 1536) : (Ws + (size_t)(o - CD_) * 1536);
        float bias = isC ? bc[o] : bs[o - CD_];
        float scale = isC ? (1.f - g) : g;
        const float4* w4 = reinterpret_cast<const float4*>(w);
        float accv[8] = {};
        for (int k4 = 0; k4 < 384; ++k4) {
            float4 wv = w4[k4];
#pragma unroll
            for (int bi = 0; bi < 8; ++bi) {
                float4 rv = repl[bi * 384 + k4];
                float t = fmaf(wv.x, rv.x, fmaf(wv.y, rv.y, fmaf(wv.z, rv.z, wv.w * rv.w)));
                accv[bi] += t;
            }
        }
#pragma unroll
        for (int bi = 0; bi < 8; ++bi) featS[bi * FEAT_ + o] = (accv[bi] + bias) * scale;
    }
    if (tid < 8) featS[tid * FEAT_ + 320] = d_ot[b0 + tid];
    __syncthreads();

    for (int bi = 0; bi < 8; ++bi) {
        float s = 0.f, s2 = 0.f;
        for (int f = tid; f < FEAT_; f += 256) {
            float v = featS[bi * FEAT_ + f];
            s += v;
            s2 = fmaf(v, v, s2);
        }
        red[tid] = s;
        __syncthreads();
        for (int off = 128; off > 0; off >>= 1) {
            if (tid < off) red[tid] += red[tid + off];
            __syncthreads();
        }
        float mu = red[0] / (float)FEAT_;
        __syncthreads();
        red[tid] = s2;
        __syncthreads();
        for (int off = 128; off > 0; off >>= 1) {
            if (tid < off) red[tid] += red[tid + off];
            __syncthreads();
        }
        float var = fmaxf(red[0] / (float)FEAT_ - mu * mu, 0.f);
        float rstd = 1.0f / sqrtf(var + LN_EPS_);
        __syncthreads();

        float l0 = 0.f, l1 = 0.f;
        for (int f = tid; f < FEAT_; f += 256) {
            float nv = (featS[bi * FEAT_ + f] - mu) * rstd * lng[f] + lnb[f];
            l0 = fmaf(nv, Wcls[f], l0);
            l1 = fmaf(nv, Wcls[FEAT_ + f], l1);
        }
        red[tid] = l0;
        __syncthreads();
        for (int off = 128; off > 0; off >>= 1) {
            if (tid < off) red[tid] += red[tid + off];
            __syncthreads();
        }
        float L0 = red[0];
        __syncthreads();
        red[tid] = l1;
        __syncthreads();
        for (int off = 128; off > 0; off >>= 1) {
            if (tid < off) red[tid] += red[tid + off];
            __syncthreads();
        }
        if (tid == 0) {
            out[(size_t)(b0 + bi) * 2 + 0] = L0 + bcls[0];
            out[(size_t)(b0 + bi) * 2 + 1] = red[0] + bcls[1];
        }
        __syncthreads();
    }
}

// ---------------------------------------------------------------------------
// Kernel 5/6: ortho = mean((Wc @ Ws^T)^2), deterministic two-stage reduction
// ---------------------------------------------------------------------------
__global__ __launch_bounds__(256) void k_ortho(const float* __restrict__ Wc,
                                               const float* __restrict__ Ws,
                                               float* __restrict__ part) {
    int i = blockIdx.x;    // Wc row, 0..191
    int tid = threadIdx.x;
    __shared__ float wrow[1536];
    __shared__ float tmp[256];
    for (int k = tid; k < 1536; k += 256) wrow[k] = Wc[(size_t)i * 1536 + k];
    __syncthreads();
    int j = tid & 127, h = tid >> 7;    // split each dot across 2 threads
    const float* wsr = Ws + (size_t)j * 1536 + h * 768;
    const float* wr = wrow + h * 768;
    float s = 0.f;
    for (int k = 0; k < 768; ++k) s = fmaf(wr[k], wsr[k], s);
    tmp[tid] = s;
    __syncthreads();
    if (tid < 128) {
        float d = tmp[tid] + tmp[tid + 128];
        tmp[tid] = d * d;
    }
    __syncthreads();
    for (int off = 64; off > 0; off >>= 1) {
        if (tid < off) tmp[tid] += tmp[tid + off];
        __syncthreads();
    }
    if (tid == 0) part[i] = tmp[0];
}

__global__ __launch_bounds__(256) void k_ortho2(const float* __restrict__ part,
                                                float* __restrict__ out) {
    int tid = threadIdx.x;
    __shared__ float red[256];
    red[tid] = (tid < CD_) ? part[tid] : 0.f;
    __syncthreads();
    for (int off = 128; off > 0; off >>= 1) {
        if (tid < off) red[tid] += red[tid + off];
        __syncthreads();
    }
    if (tid == 0) out[(size_t)B_ * 2] = red[0] / (float)(CD_ * SD_);
}

// ---------------------------------------------------------------------------
extern "C" void kernel_launch(void* const* d_in, const int* in_sizes, int n_in,
                              void* d_out, int out_size, void* d_ws, size_t ws_size,
                              hipStream_t stream) {
    const float* H    = (const float*)d_in[0];
    const int*   tt   = (const int*)d_in[1];
    const int*   attn = (const int*)d_in[2];
    const float* Wc   = (const float*)d_in[3];
    const float* bc   = (const float*)d_in[4];
    const float* Ws   = (const float*)d_in[5];
    const float* bs   = (const float*)d_in[6];
    const float* gate = (const float*)d_in[7];
    const float* lng  = (const float*)d_in[8];
    const float* lnb  = (const float*)d_in[9];
    const float* Wcls = (const float*)d_in[10];
    const float* bcls = (const float*)d_in[11];
    const float* dirs = (const float*)d_in[12];

    float* ws   = (float*)d_ws;
    float* rep  = ws + REP_OFF;
    float* dn   = ws + DIRS_OFF;
    float* dot  = ws + DOT_OFF;
    float* part = ws + PART_OFF;
    float* out  = (float*)d_out;

    hipMemsetAsync(dot, 0, B_ * sizeof(float), stream);   // d_ot max-accumulator init (0.0f)

    k_rep<<<B_, 256, 0, stream>>>(H, tt, attn, rep);
    k_dirs<<<P_, 256, 0, stream>>>(dirs, dn);
    k_projsort<<<dim3(B_, 2), 256, 0, stream>>>(H, tt, attn, dn, dot);
    k_head<<<B_ / 8, 256, 0, stream>>>(rep, Wc, bc, Ws, bs, gate, lng, lnb, Wcls, bcls, dot, out);
    k_ortho<<<CD_, 256, 0, stream>>>(Wc, Ws, part);
    k_ortho2<<<1, 256, 0, stream>>>(part, out);
}

// Round 3
// 307.614 us; speedup vs baseline: 2.8962x; 1.2221x over previous
//
#include <hip/hip_runtime.h>
#include <hip/hip_bf16.h>

// Problem constants
constexpr int B_ = 512;
constexpr int T_ = 128;
constexpr int D_ = 768;
constexpr int CD_ = 192;
constexpr int SD_ = 128;
constexpr int P_ = 128;
constexpr int FEAT_ = 321;   // CD + SD + 1
constexpr float LN_EPS_ = 1e-5f;

// Workspace layout (in floats)
constexpr size_t REP_SZ   = (size_t)B_ * 2 * D_;     // 786432 floats
constexpr size_t DN16_FLT = (size_t)P_ * D_ / 2;     // 98304 u16 = 49152 floats

typedef __attribute__((ext_vector_type(8))) short short8;   // 8 bf16 (4 VGPRs)
typedef __attribute__((ext_vector_type(4))) float f32x4;

// float -> bf16 RNE
__device__ inline unsigned short f2bf(float x) {
    unsigned u = __float_as_uint(x);
    return (unsigned short)((u + 0x7FFFu + ((u >> 16) & 1u)) >> 16);
}

// ---------------------------------------------------------------------------
// Kernel 1: dirs_n = dirs / ||dirs||, emitted as bf16  (one block per dir)
// ---------------------------------------------------------------------------
__global__ __launch_bounds__(256) void k_dirs(const float* __restrict__ dirs,
                                              unsigned short* __restrict__ dn16) {
    int p = blockIdx.x;
    int tid = threadIdx.x;
    float s = 0.f;
    for (int d = tid; d < D_; d += 256) {
        float v = dirs[(size_t)p * D_ + d];
        s = fmaf(v, v, s);
    }
    __shared__ float red[256];
    red[tid] = s;
    __syncthreads();
    for (int off = 128; off > 0; off >>= 1) {
        if (tid < off) red[tid] += red[tid + off];
        __syncthreads();
    }
    float inv = 1.0f / sqrtf(red[0]);
    for (int d = tid; d < D_; d += 256) {
        dn16[(size_t)p * D_ + d] = f2bf(dirs[(size_t)p * D_ + d] * inv);
    }
}

// ---------------------------------------------------------------------------
// Kernel 2: MFMA proj GEMM (bf16) + fused rep (y==0) + key-rank + paired diff
// grid = (B, 2): block handles batch b, dir columns [half*64, half*64+64)
// ---------------------------------------------------------------------------
constexpr int KB_ = 32;          // K-step
constexpr int SA_ = 40;          // LDS stride in bf16 elems (80 B)
constexpr int BOFF_ = 128 * SA_;                 // B tile offset (u16)
constexpr int STAGE_U16_ = BOFF_ + 64 * SA_;     // 7680 u16 = 15360 B
constexpr int RSTR_ = 12;        // rep-reduce buffer stride (floats)

__global__ __launch_bounds__(256) void k_projsort(const float* __restrict__ H,
                                                  const int* __restrict__ tt,
                                                  const int* __restrict__ attn,
                                                  const unsigned short* __restrict__ dn16,
                                                  float* __restrict__ rep,
                                                  float* __restrict__ d_ot) {
    const int b = blockIdx.x;
    const int p0 = blockIdx.y * 64;
    const bool doRep = (blockIdx.y == 0);
    const int tid = threadIdx.x;

    __shared__ float proj[T_ * 64];                              // 32 KB (redbuf overlay during GEMM)
    __shared__ __align__(16) unsigned short stage[STAGE_U16_];   // 15 KB
    __shared__ float m0s[T_], m1s[T_];
    __shared__ unsigned char rlist[T_];
    __shared__ int ncnt[2];
    __shared__ float dred[256];

    // rank->t index tables overlay the (dead after GEMM) stage buffer
    unsigned char* xb = (unsigned char*)stage;           // [64][64]
    unsigned char* yb = xb + 64 * 64;                    // [64][64]
    float* redbuf = proj;                                // [256][RSTR_] overlay

    // --- phase 0: masks, counts, group-compacted row list ---
    if (tid < 2) ncnt[tid] = 0;
    __syncthreads();
    if (tid < T_) {
        int t = tt[b * T_ + tid];
        int a = attn[b * T_ + tid];
        float m0 = (t == 0 && a == 1) ? 1.f : 0.f;
        float m1 = (t == 1 && a == 1) ? 1.f : 0.f;
        m0s[tid] = m0;
        m1s[tid] = m1;
        if (m0 > 0.f) atomicAdd(&ncnt[0], 1);
        if (m1 > 0.f) atomicAdd(&ncnt[1], 1);
    }
    __syncthreads();
    const int n0 = ncnt[0], n1 = ncnt[1];
    const int ntot = n0 + n1;
    const float inv0 = 1.f / (float)max(n0, 1);
    const float inv1 = 1.f / (float)max(n1, 1);
    if (tid < T_) {
        float me0 = m0s[tid], me1 = m1s[tid];
        if (me0 > 0.f || me1 > 0.f) {
            bool g1 = (me1 > 0.f);
            const float* ms = g1 ? m1s : m0s;
            int pos = g1 ? n0 : 0;
            for (int j = 0; j < tid; ++j) pos += (ms[j] > 0.f) ? 1 : 0;
            rlist[pos] = (unsigned char)tid;
        }
    }
    // rlist read only in phase 2 (many syncs later); m0s valid now.

    // --- phase 1: GEMM proj[t][p] = sum_k H[b,t,k] * dn[p0+p,k] via bf16 MFMA,
    //     with fused rep (masked column sums) on the y==0 block. ---
    const int wv = tid >> 6;          // wave 0..3
    const int wr = wv >> 1;           // row half
    const int wc = wv & 1;            // col half
    const int lane = tid & 63;
    const int fr = lane & 15;         // fragment row/col
    const int fk = (lane >> 4) * 8;   // fragment k offset
    const float* Hb = H + (size_t)b * T_ * D_;
    float* repb = rep + (size_t)b * 2 * D_;

    const int arow = tid >> 3;        // 0..31 (A staging base row)
    const int akq  = (tid & 7) * 4;   // 0..28 (A staging k offset)
    const int brow = tid >> 2;        // 0..63 (B staging row)
    const int bkq  = (tid & 3) * 8;   // 0..24 (B staging k offset)

    float m0v[4], m1v[4];
#pragma unroll
    for (int j = 0; j < 4; ++j) {
        m0v[j] = m0s[arow + 32 * j];
        m1v[j] = m1s[arow + 32 * j];
    }

    f32x4 acc[4][2];
#pragma unroll
    for (int m = 0; m < 4; ++m)
#pragma unroll
        for (int n = 0; n < 2; ++n) acc[m][n] = (f32x4){0.f, 0.f, 0.f, 0.f};

    for (int k0 = 0; k0 < D_; k0 += KB_) {
        __syncthreads();   // prev-iter frag reads + redbuf reduce done
        float s0p[4] = {0.f, 0.f, 0.f, 0.f};
        float s1p[4] = {0.f, 0.f, 0.f, 0.f};
        // stage A: 128 rows x 32 k fp32 -> bf16 (4 float4 chunks / thread)
#pragma unroll
        for (int j = 0; j < 4; ++j) {
            int row = arow + 32 * j;
            float4 h = *reinterpret_cast<const float4*>(Hb + (size_t)row * D_ + k0 + akq);
            ushort4 v;
            v.x = f2bf(h.x); v.y = f2bf(h.y); v.z = f2bf(h.z); v.w = f2bf(h.w);
            *reinterpret_cast<ushort4*>(&stage[row * SA_ + akq]) = v;
            if (doRep) {
                float m0 = m0v[j], m1 = m1v[j];
                s0p[0] = fmaf(h.x, m0, s0p[0]); s1p[0] = fmaf(h.x, m1, s1p[0]);
                s0p[1] = fmaf(h.y, m0, s0p[1]); s1p[1] = fmaf(h.y, m1, s1p[1]);
                s0p[2] = fmaf(h.z, m0, s0p[2]); s1p[2] = fmaf(h.z, m1, s1p[2]);
                s0p[3] = fmaf(h.w, m0, s0p[3]); s1p[3] = fmaf(h.w, m1, s1p[3]);
                if (j == 0 && arow == 0) {    // cls = H[b,0,:] exact fp32
                    *reinterpret_cast<float4*>(repb + k0 + akq) = h;
                }
            }
        }
        // stage B: 64 rows x 32 k bf16 (1 short8 / thread)
        {
            short8 dv = *reinterpret_cast<const short8*>(dn16 + (size_t)(p0 + brow) * D_ + k0 + bkq);
            *reinterpret_cast<short8*>(&stage[BOFF_ + brow * SA_ + bkq]) = dv;
        }
        if (doRep) {
            *reinterpret_cast<float4*>(&redbuf[tid * RSTR_]) = (float4){s0p[0], s0p[1], s0p[2], s0p[3]};
            *reinterpret_cast<float4*>(&redbuf[tid * RSTR_ + 4]) = (float4){s1p[0], s1p[1], s1p[2], s1p[3]};
        }
        __syncthreads();
        short8 a_f[4], b_f[2];
#pragma unroll
        for (int m = 0; m < 4; ++m) {
            int r = 64 * wr + 16 * m + fr;
            a_f[m] = *reinterpret_cast<const short8*>(&stage[r * SA_ + fk]);
        }
#pragma unroll
        for (int n = 0; n < 2; ++n) {
            int r = 32 * wc + 16 * n + fr;
            b_f[n] = *reinterpret_cast<const short8*>(&stage[BOFF_ + r * SA_ + fk]);
        }
#pragma unroll
        for (int m = 0; m < 4; ++m)
#pragma unroll
            for (int n = 0; n < 2; ++n)
                acc[m][n] = __builtin_amdgcn_mfma_f32_16x16x32_bf16(a_f[m], b_f[n], acc[m][n], 0, 0, 0);

        // rep reduce: 32 columns of this k-slice, wave 0 lanes 0..31
        if (doRep && tid < 32) {
            int kqIdx = tid >> 2, ci = tid & 3;
            float s0 = 0.f, s1 = 0.f;
#pragma unroll 4
            for (int g = 0; g < 32; ++g) {
                int base = (8 * g + kqIdx) * RSTR_ + ci;
                s0 += redbuf[base];
                s1 += redbuf[base + 4];
            }
            repb[D_ + k0 + tid] = s0 * inv0 - s1 * inv1;
        }
    }
    __syncthreads();
    // write proj: C/D layout col=lane&15, row=(lane>>4)*4+reg
#pragma unroll
    for (int m = 0; m < 4; ++m)
#pragma unroll
        for (int n = 0; n < 2; ++n) {
            int row0 = 64 * wr + 16 * m + (lane >> 4) * 4;
            int col = 32 * wc + 16 * n + fr;
#pragma unroll
            for (int r = 0; r < 4; ++r) proj[(row0 + r) * 64 + col] = acc[m][n][r];
        }
    __syncthreads();

    // --- phase 2: ranking via sortable-u32 keys ---
    const int mmv = min(n0, n1);      // <= 64 since n0+n1 <= 128
    const int c = tid & 63;
    const int q = tid >> 6;           // wave-uniform
    unsigned kv[32];
    int cnt[32];
#pragma unroll
    for (int ii = 0; ii < 32; ++ii) {
        int p = q * 32 + ii;
        unsigned key = 0xFFFFFFFFu;
        if (p < ntot) {
            int t = rlist[p];
            unsigned u = __float_as_uint(proj[t * 64 + c]);
            unsigned su = u ^ (unsigned)(((int)u >> 31) | 0x80000000);
            key = ((unsigned)(p >= n0) << 31) | ((su >> 8) << 7) | (unsigned)p;
        }
        kv[ii] = key;
        cnt[ii] = 0;
    }
    int lo, hi;
    {
        int plo = q * 32, phi = q * 32 + 32;
        if (phi <= n0)      { lo = 0;  hi = n0;   }   // pure group-0 chunk
        else if (plo >= n0) { lo = n0; hi = ntot; }   // pure group-1 chunk
        else                { lo = 0;  hi = ntot; }   // straddler
    }
    for (int j = lo; j < hi; ++j) {
        int tj = rlist[j];
        unsigned u = __float_as_uint(proj[tj * 64 + c]);
        unsigned su = u ^ (unsigned)(((int)u >> 31) | 0x80000000);
        unsigned kw = ((unsigned)(j >= n0) << 31) | ((su >> 8) << 7) | (unsigned)j;
#pragma unroll
        for (int ii = 0; ii < 32; ++ii) cnt[ii] += (kw < kv[ii]) ? 1 : 0;
    }
#pragma unroll
    for (int ii = 0; ii < 32; ++ii) {
        int p = q * 32 + ii;
        if (p < ntot) {
            int rank = cnt[ii] - ((p >= n0 && lo == 0) ? n0 : 0);
            if (rank < mmv) {
                unsigned char* buf = (p >= n0) ? yb : xb;
                buf[rank * 64 + c] = rlist[p];
            }
        }
    }
    __syncthreads();

    // --- phase 3: paired diff per column, max over columns ---
    float part = 0.f;
    for (int r = q; r < mmv; r += 4) {
        int xt = xb[r * 64 + c], yt = yb[r * 64 + c];
        part += fabsf(proj[xt * 64 + c] - proj[yt * 64 + c]);
    }
    dred[tid] = part;
    __syncthreads();
    if (tid < 64) {
        float s = dred[tid] + dred[tid + 64] + dred[tid + 128] + dred[tid + 192];
        dred[tid] = s / (float)max(mmv, 1);
    }
    __syncthreads();
    if (tid == 0) {
        float m = dred[0];
        for (int i = 1; i < 64; ++i) m = fmaxf(m, dred[i]);
        atomicMax((unsigned int*)&d_ot[b], __float_as_uint(m));  // m >= 0
    }
}

// ---------------------------------------------------------------------------
// Kernel 3: head — C/S GEMV + gate + LayerNorm + logits.
// 320 threads (1 output each), 4 batches per block, wave-parallel LN.
// ---------------------------------------------------------------------------
__global__ __launch_bounds__(320) void k_head(const float* __restrict__ rep,
                                              const float* __restrict__ Wc,
                                              const float* __restrict__ bc,
                                              const float* __restrict__ Ws,
                                              const float* __restrict__ bs,
                                              const float* __restrict__ gate,
                                              const float* __restrict__ lng,
                                              const float* __restrict__ lnb,
                                              const float* __restrict__ Wcls,
                                              const float* __restrict__ bcls,
                                              const float* __restrict__ d_ot,
                                              float* __restrict__ out) {
    int b0 = blockIdx.x * 4;
    int tid = threadIdx.x;
    __shared__ __align__(16) float repS[4 * 1536];   // 24 KB
    __shared__ float featS[4 * FEAT_];

    const float4* repg = reinterpret_cast<const float4*>(rep + (size_t)b0 * 1536);
    float4* repl = reinterpret_cast<float4*>(repS);
    for (int i = tid; i < 1536; i += 320) repl[i] = repg[i];
    __syncthreads();

    float g = 1.f / (1.f + expf(-gate[0]));

    {   // each thread: one output o over 4 batches
        int o = tid;  // 0..319
        bool isC = o < CD_;
        const float* w = isC ? (Wc + (size_t)o * 1536) : (Ws + (size_t)(o - CD_) * 1536);
        float bias = isC ? bc[o] : bs[o - CD_];
        float scale = isC ? (1.f - g) : g;
        const float4* w4 = reinterpret_cast<const float4*>(w);
        float a0 = 0.f, a1 = 0.f, a2 = 0.f, a3 = 0.f;
        for (int k4 = 0; k4 < 384; ++k4) {
            float4 wv = w4[k4];
            float4 r0 = repl[k4];
            float4 r1 = repl[384 + k4];
            float4 r2 = repl[768 + k4];
            float4 r3 = repl[1152 + k4];
            a0 += fmaf(wv.x, r0.x, fmaf(wv.y, r0.y, fmaf(wv.z, r0.z, wv.w * r0.w)));
            a1 += fmaf(wv.x, r1.x, fmaf(wv.y, r1.y, fmaf(wv.z, r1.z, wv.w * r1.w)));
            a2 += fmaf(wv.x, r2.x, fmaf(wv.y, r2.y, fmaf(wv.z, r2.z, wv.w * r2.w)));
            a3 += fmaf(wv.x, r3.x, fmaf(wv.y, r3.y, fmaf(wv.z, r3.z, wv.w * r3.w)));
        }
        featS[0 * FEAT_ + o] = (a0 + bias) * scale;
        featS[1 * FEAT_ + o] = (a1 + bias) * scale;
        featS[2 * FEAT_ + o] = (a2 + bias) * scale;
        featS[3 * FEAT_ + o] = (a3 + bias) * scale;
    }
    if (tid < 4) featS[tid * FEAT_ + 320] = d_ot[b0 + tid];
    __syncthreads();

    int w = tid >> 6, lane = tid & 63;
    if (w < 4) {   // wave w handles batch b0+w
        const float* f = featS + w * FEAT_;
        float s = 0.f, s2 = 0.f;
        for (int i = lane; i < FEAT_; i += 64) {
            float v = f[i];
            s += v;
            s2 = fmaf(v, v, s2);
        }
#pragma unroll
        for (int off = 32; off > 0; off >>= 1) {
            s += __shfl_xor(s, off);
            s2 += __shfl_xor(s2, off);
        }
        float mu = s * (1.f / (float)FEAT_);
        float var = fmaxf(s2 * (1.f / (float)FEAT_) - mu * mu, 0.f);
        float rstd = 1.0f / sqrtf(var + LN_EPS_);
        float l0 = 0.f, l1 = 0.f;
        for (int i = lane; i < FEAT_; i += 64) {
            float nv = (f[i] - mu) * rstd * lng[i] + lnb[i];
            l0 = fmaf(nv, Wcls[i], l0);
            l1 = fmaf(nv, Wcls[FEAT_ + i], l1);
        }
#pragma unroll
        for (int off = 32; off > 0; off >>= 1) {
            l0 += __shfl_xor(l0, off);
            l1 += __shfl_xor(l1, off);
        }
        if (lane == 0) {
            out[(size_t)(b0 + w) * 2 + 0] = l0 + bcls[0];
            out[(size_t)(b0 + w) * 2 + 1] = l1 + bcls[1];
        }
    }
}

// ---------------------------------------------------------------------------
// Kernel 4/5: ortho = mean((Wc @ Ws^T)^2), deterministic two-stage reduction
// ---------------------------------------------------------------------------
__global__ __launch_bounds__(256) void k_ortho(const float* __restrict__ Wc,
                                               const float* __restrict__ Ws,
                                               float* __restrict__ part) {
    int i = blockIdx.x;    // Wc row, 0..191
    int tid = threadIdx.x;
    __shared__ float wrow[1536];
    __shared__ float tmp[256];
    for (int k = tid; k < 1536; k += 256) wrow[k] = Wc[(size_t)i * 1536 + k];
    __syncthreads();
    int j = tid & 127, h = tid >> 7;    // split each dot across 2 threads
    const float* wsr = Ws + (size_t)j * 1536 + h * 768;
    const float* wr = wrow + h * 768;
    float s = 0.f;
    for (int k = 0; k < 768; ++k) s = fmaf(wr[k], wsr[k], s);
    tmp[tid] = s;
    __syncthreads();
    if (tid < 128) {
        float d = tmp[tid] + tmp[tid + 128];
        tmp[tid] = d * d;
    }
    __syncthreads();
    for (int off = 64; off > 0; off >>= 1) {
        if (tid < off) tmp[tid] += tmp[tid + off];
        __syncthreads();
    }
    if (tid == 0) part[i] = tmp[0];
}

__global__ __launch_bounds__(256) void k_ortho2(const float* __restrict__ part,
                                                float* __restrict__ out) {
    int tid = threadIdx.x;
    __shared__ float red[256];
    red[tid] = (tid < CD_) ? part[tid] : 0.f;
    __syncthreads();
    for (int off = 128; off > 0; off >>= 1) {
        if (tid < off) red[tid] += red[tid + off];
        __syncthreads();
    }
    if (tid == 0) out[(size_t)B_ * 2] = red[0] / (float)(CD_ * SD_);
}

// ---------------------------------------------------------------------------
extern "C" void kernel_launch(void* const* d_in, const int* in_sizes, int n_in,
                              void* d_out, int out_size, void* d_ws, size_t ws_size,
                              hipStream_t stream) {
    const float* H    = (const float*)d_in[0];
    const int*   tt   = (const int*)d_in[1];
    const int*   attn = (const int*)d_in[2];
    const float* Wc   = (const float*)d_in[3];
    const float* bc   = (const float*)d_in[4];
    const float* Ws   = (const float*)d_in[5];
    const float* bs   = (const float*)d_in[6];
    const float* gate = (const float*)d_in[7];
    const float* lng  = (const float*)d_in[8];
    const float* lnb  = (const float*)d_in[9];
    const float* Wcls = (const float*)d_in[10];
    const float* bcls = (const float*)d_in[11];
    const float* dirs = (const float*)d_in[12];

    float* ws    = (float*)d_ws;
    float* rep   = ws;                                   // [B][1536] fp32
    unsigned short* dn16 = (unsigned short*)(ws + REP_SZ);  // [P][D] bf16
    float* dot   = ws + REP_SZ + DN16_FLT;               // [B]
    float* part  = dot + B_;                             // [CD]
    float* out   = (float*)d_out;

    hipMemsetAsync(dot, 0, B_ * sizeof(float), stream);  // d_ot max-accumulator init

    k_dirs<<<P_, 256, 0, stream>>>(dirs, dn16);
    k_projsort<<<dim3(B_, 2), 256, 0, stream>>>(H, tt, attn, dn16, rep, dot);
    k_head<<<B_ / 4, 320, 0, stream>>>(rep, Wc, bc, Ws, bs, gate, lng, lnb, Wcls, bcls, dot, out);
    k_ortho<<<CD_, 256, 0, stream>>>(Wc, Ws, part);
    k_ortho2<<<1, 256, 0, stream>>>(part, out);
}